// Round 1
// baseline (1271.943 us; speedup 1.0000x reference)
//
#include <hip/hip_runtime.h>
#include <cstdint>

#define NTOK 4096
#define DDIM 1024
#define HDIM 4096
#define ODIM 1024
#define NEXP 8
#define NSLOT (2*NTOK)

typedef __bf16 bf16x8 __attribute__((ext_vector_type(8)));
typedef float  f32x4  __attribute__((ext_vector_type(4)));

__device__ __forceinline__ unsigned short f2bf(float f) {
    union { float f; unsigned int u; } v; v.f = f;
    unsigned int r = (v.u + 0x7FFF + ((v.u >> 16) & 1)) >> 16;
    return (unsigned short)r;
}

typedef const void __attribute__((address_space(1)))* gas_ptr;
typedef void       __attribute__((address_space(3)))* las_ptr;

// ---------------- gate: logits = relu(x@Wg), top-2 with lowest-index tie-break ----
__global__ void gate_kernel(const float* __restrict__ x, const float* __restrict__ Wg,
                            int2* __restrict__ sel, float2* __restrict__ wts,
                            int* __restrict__ counts) {
    int wave = threadIdx.x >> 6;
    int lane = threadIdx.x & 63;
    int n = blockIdx.x * 4 + wave;
    float acc[NEXP];
#pragma unroll
    for (int e = 0; e < NEXP; e++) acc[e] = 0.f;
    const float* xr = x + (size_t)n * DDIM;
    for (int i = 0; i < DDIM / 64; i++) {
        int d = i * 64 + lane;
        float xv = xr[d];
        const float* wr = Wg + d * NEXP;
#pragma unroll
        for (int e = 0; e < NEXP; e++) acc[e] = fmaf(xv, wr[e], acc[e]);
    }
#pragma unroll
    for (int e = 0; e < NEXP; e++) {
#pragma unroll
        for (int off = 32; off >= 1; off >>= 1)
            acc[e] += __shfl_xor(acc[e], off, 64);
    }
    if (lane == 0) {
        float l0 = -1e30f, l1 = -1e30f; int e0 = 0, e1 = 0;
#pragma unroll
        for (int e = 0; e < NEXP; e++) {
            float v = fmaxf(acc[e], 0.f);   // relu before softmax
            if (v > l0)      { l1 = l0; e1 = e0; l0 = v; e0 = e; }
            else if (v > l1) { l1 = v;  e1 = e; }
        }
        // softmax Z cancels: w0 = p0/(p0+p1) = 1/(1+exp(l1-l0))
        float w0 = 1.f / (1.f + expf(l1 - l0));
        sel[n] = make_int2(e0, e1);
        wts[n] = make_float2(w0, 1.f - w0);
        atomicAdd(&counts[e0], 1);
        atomicAdd(&counts[e1], 1);
    }
}

__global__ void scan_kernel(const int* __restrict__ counts, int* __restrict__ offsets,
                            int* __restrict__ cursor) {
    if (threadIdx.x == 0 && blockIdx.x == 0) {
        int s = 0;
        for (int e = 0; e < NEXP; e++) { offsets[e] = s; cursor[e] = s; s += counts[e]; }
        offsets[NEXP] = s;
    }
}

__global__ void assign_kernel(const int2* __restrict__ sel, const float2* __restrict__ wts,
                              int* __restrict__ cursor,
                              int* __restrict__ slot_token, float* __restrict__ slot_weight) {
    int n = blockIdx.x * blockDim.x + threadIdx.x;
    if (n >= NTOK) return;
    int2 s = sel[n]; float2 w = wts[n];
    int p0 = atomicAdd(&cursor[s.x], 1);
    slot_token[p0] = n; slot_weight[p0] = w.x;
    int p1 = atomicAdd(&cursor[s.y], 1);
    slot_token[p1] = n; slot_weight[p1] = w.y;
}

// ---------------- fp32 -> bf16 cast of x ----------------
__global__ void cast_x_kernel(const float* __restrict__ x, unsigned short* __restrict__ xb) {
    int i = blockIdx.x * blockDim.x + threadIdx.x;   // one float4 per thread
    float4 v = ((const float4*)x)[i];
    ushort4 o;
    o.x = f2bf(v.x); o.y = f2bf(v.y); o.z = f2bf(v.z); o.w = f2bf(v.w);
    ((ushort4*)xb)[i] = o;
}

// ---------------- transpose+cast: src [R][C] fp32 -> dst [C][R] bf16, per expert (z) ----
__global__ void transpose_cast_kernel(const float* __restrict__ src, unsigned short* __restrict__ dst,
                                      int R, int C) {
    __shared__ float tile[32][33];
    int e = blockIdx.z;
    const float* s = src + (size_t)e * R * C;
    unsigned short* d = dst + (size_t)e * R * C;
    int tx = threadIdx.x, ty = threadIdx.y;          // block (32,8)
    int c0 = blockIdx.x * 32, r0 = blockIdx.y * 32;
#pragma unroll
    for (int i = 0; i < 4; i++)
        tile[ty + i * 8][tx] = s[(size_t)(r0 + ty + i * 8) * C + (c0 + tx)];
    __syncthreads();
#pragma unroll
    for (int i = 0; i < 4; i++)
        d[(size_t)(c0 + ty + i * 8) * R + (r0 + tx)] = f2bf(tile[tx][ty + i * 8]);
}

// ---------------- tiled MFMA GEMM over compacted expert rows (m97 structure) -------
// MODE 1: A = xb gathered via slot_token, B = W1T[e][H][D], epi: +b1, relu, store bf16 h
// MODE 2: A = h rows (contiguous slots), B = W2T[e][O][H], epi: +b2, relu, *w, atomicAdd out
template <int MODE, int KDIM, int NDIM>
__global__ __launch_bounds__(256) void moe_gemm_kernel(
    const unsigned short* __restrict__ A,
    const unsigned short* __restrict__ B,
    const float* __restrict__ bias,
    const int* __restrict__ offsets,
    const int* __restrict__ slot_token,
    const float* __restrict__ slot_weight,
    unsigned short* __restrict__ h,
    float* __restrict__ out) {

    int e  = blockIdx.x >> 5;
    int rt = blockIdx.x & 31;
    int base = offsets[e];
    int cnt  = offsets[e + 1] - base;
    if (rt * 128 >= cnt) return;
    int slotBase = base + rt * 128;

    __shared__ __align__(16) unsigned short As[128 * 32];
    __shared__ __align__(16) unsigned short Bs[128 * 32];

    int tid = threadIdx.x;
    int w = tid >> 6, l = tid & 63;
    int quad = l >> 4, lr = l & 15;
    int wm = w & 1, wn = w >> 1;

    // staging rows for global_load_lds (chunk c = 2w+j covers rows 16c..16c+15)
    int srow0 = 32 * w + (l >> 2);
    int srow1 = srow0 + 16;
    int kb = (l & 3) * 8;                 // element offset within 32-elem row

    const unsigned short *ag0, *ag1;
    if constexpr (MODE == 1) {
        int t0 = (rt * 128 + srow0 < cnt) ? slot_token[slotBase + srow0] : 0;
        int t1 = (rt * 128 + srow1 < cnt) ? slot_token[slotBase + srow1] : 0;
        ag0 = A + (size_t)t0 * KDIM + kb;
        ag1 = A + (size_t)t1 * KDIM + kb;
    } else {
        int s0 = min(slotBase + srow0, NSLOT - 1);
        int s1 = min(slotBase + srow1, NSLOT - 1);
        ag0 = A + (size_t)s0 * KDIM + kb;
        ag1 = A + (size_t)s1 * KDIM + kb;
    }
    int colBase = blockIdx.y * 128;
    const unsigned short* Be = B + (size_t)e * NDIM * KDIM;
    const unsigned short* bg0 = Be + (size_t)(colBase + srow0) * KDIM + kb;
    const unsigned short* bg1 = Be + (size_t)(colBase + srow1) * KDIM + kb;

    unsigned short* AsC0 = As + (2 * w + 0) * 512;   // 1 KiB per chunk
    unsigned short* AsC1 = As + (2 * w + 1) * 512;
    unsigned short* BsC0 = Bs + (2 * w + 0) * 512;
    unsigned short* BsC1 = Bs + (2 * w + 1) * 512;

    f32x4 zero = {0.f, 0.f, 0.f, 0.f};
    f32x4 acc[4][4];
#pragma unroll
    for (int m = 0; m < 4; m++)
#pragma unroll
        for (int n = 0; n < 4; n++) acc[m][n] = zero;

    for (int k0 = 0; k0 < KDIM; k0 += 32) {
        __builtin_amdgcn_global_load_lds((gas_ptr)(ag0 + k0), (las_ptr)AsC0, 16, 0, 0);
        __builtin_amdgcn_global_load_lds((gas_ptr)(ag1 + k0), (las_ptr)AsC1, 16, 0, 0);
        __builtin_amdgcn_global_load_lds((gas_ptr)(bg0 + k0), (las_ptr)BsC0, 16, 0, 0);
        __builtin_amdgcn_global_load_lds((gas_ptr)(bg1 + k0), (las_ptr)BsC1, 16, 0, 0);
        __syncthreads();
        bf16x8 af[4], bf[4];
#pragma unroll
        for (int m = 0; m < 4; m++)
            af[m] = *(const bf16x8*)&As[(wm * 64 + m * 16 + lr) * 32 + quad * 8];
#pragma unroll
        for (int n = 0; n < 4; n++)
            bf[n] = *(const bf16x8*)&Bs[(wn * 64 + n * 16 + lr) * 32 + quad * 8];
#pragma unroll
        for (int m = 0; m < 4; m++)
#pragma unroll
            for (int n = 0; n < 4; n++)
                acc[m][n] = __builtin_amdgcn_mfma_f32_16x16x32_bf16(af[m], bf[n], acc[m][n], 0, 0, 0);
        __syncthreads();
    }

    if constexpr (MODE == 1) {
        const float* bv = bias + e * NDIM;
#pragma unroll
        for (int n = 0; n < 4; n++) {
            int gc = colBase + wn * 64 + n * 16 + lr;
            float b = bv[gc];
#pragma unroll
            for (int m = 0; m < 4; m++) {
                int rloc = wm * 64 + m * 16 + quad * 4;
#pragma unroll
                for (int i = 0; i < 4; i++) {
                    int r = rloc + i;
                    if (rt * 128 + r < cnt) {
                        float v = fmaxf(acc[m][n][i] + b, 0.f);
                        h[(size_t)(slotBase + r) * NDIM + gc] = f2bf(v);
                    }
                }
            }
        }
    } else {
        const float* bv = bias + e * NDIM;
#pragma unroll
        for (int m = 0; m < 4; m++) {
            int rloc = wm * 64 + m * 16 + quad * 4;
#pragma unroll
            for (int i = 0; i < 4; i++) {
                int r = rloc + i;
                if (rt * 128 + r >= cnt) continue;
                int s = slotBase + r;
                int tok = slot_token[s];
                float wgt = slot_weight[s];
                float* orow = out + (size_t)tok * ODIM;
#pragma unroll
                for (int n = 0; n < 4; n++) {
                    int gc = colBase + wn * 64 + n * 16 + lr;
                    float v = fmaxf(acc[m][n][i] + bv[gc], 0.f) * wgt;
                    atomicAdd(&orow[gc], v);
                }
            }
        }
    }
}

extern "C" void kernel_launch(void* const* d_in, const int* in_sizes, int n_in,
                              void* d_out, int out_size, void* d_ws, size_t ws_size,
                              hipStream_t stream) {
    const float* x  = (const float*)d_in[0];
    const float* Wg = (const float*)d_in[1];
    const float* W1 = (const float*)d_in[2];
    const float* b1 = (const float*)d_in[3];
    const float* W2 = (const float*)d_in[4];
    const float* b2 = (const float*)d_in[5];
    float* out = (float*)d_out;

    char* ws = (char*)d_ws;
    int*    counts      = (int*)(ws + 0);
    int*    cursor      = (int*)(ws + 64);
    int*    offsets     = (int*)(ws + 128);
    int2*   sel         = (int2*)(ws + 256);
    float2* wts         = (float2*)(ws + 33024);
    int*    slot_token  = (int*)(ws + 65792);
    float*  slot_weight = (float*)(ws + 98560);
    unsigned short* xb  = (unsigned short*)(ws + 131328);                 //  8 MiB
    unsigned short* W1T = (unsigned short*)(ws + 8519936);                // 64 MiB [E][H][D]
    unsigned short* W2T = (unsigned short*)(ws + 75628800);               // 64 MiB [E][O][H]
    unsigned short* hbf = (unsigned short*)(ws + 142737664);              // 64 MiB [NSLOT][H]

    hipMemsetAsync(d_out, 0, (size_t)NTOK * ODIM * sizeof(float), stream);
    hipMemsetAsync(ws, 0, 256, stream);

    gate_kernel<<<NTOK / 4, 256, 0, stream>>>(x, Wg, sel, wts, counts);
    scan_kernel<<<1, 64, 0, stream>>>(counts, offsets, cursor);
    assign_kernel<<<NTOK / 256, 256, 0, stream>>>(sel, wts, cursor, slot_token, slot_weight);

    cast_x_kernel<<<(NTOK * DDIM / 4) / 256, 256, 0, stream>>>(x, xb);
    transpose_cast_kernel<<<dim3(HDIM / 32, DDIM / 32, NEXP), dim3(32, 8), 0, stream>>>(W1, W1T, DDIM, HDIM);
    transpose_cast_kernel<<<dim3(ODIM / 32, HDIM / 32, NEXP), dim3(32, 8), 0, stream>>>(W2, W2T, HDIM, ODIM);

    moe_gemm_kernel<1, DDIM, HDIM><<<dim3(NEXP * 32, HDIM / 128), 256, 0, stream>>>(
        xb, W1T, b1, offsets, slot_token, slot_weight, hbf, nullptr);
    moe_gemm_kernel<2, HDIM, ODIM><<<dim3(NEXP * 32, ODIM / 128), 256, 0, stream>>>(
        hbf, W2T, b2, offsets, slot_token, slot_weight, nullptr, out);
}

// Round 2
// 806.504 us; speedup vs baseline: 1.5771x; 1.5771x over previous
//
#include <hip/hip_runtime.h>
#include <cstdint>

#define NTOK 4096
#define DDIM 1024
#define HDIM 4096
#define ODIM 1024
#define NEXP 8
#define NSLOT (2*NTOK)
#define MAXTILES 72

typedef __bf16 bf16x8 __attribute__((ext_vector_type(8)));
typedef float  f32x4  __attribute__((ext_vector_type(4)));
typedef unsigned short ushort8v __attribute__((ext_vector_type(8)));

__device__ __forceinline__ unsigned short f2bf(float f) {
    union { float f; unsigned int u; } v; v.f = f;
    unsigned int r = (v.u + 0x7FFF + ((v.u >> 16) & 1)) >> 16;
    return (unsigned short)r;
}

typedef const void __attribute__((address_space(1)))* gas_ptr;
typedef void       __attribute__((address_space(3)))* las_ptr;

// ---------------- gate: logits = relu(x@Wg), top-2 with lowest-index tie-break ----
__global__ void gate_kernel(const float* __restrict__ x, const float* __restrict__ Wg,
                            int2* __restrict__ sel, float2* __restrict__ wts,
                            int* __restrict__ counts) {
    int wave = threadIdx.x >> 6;
    int lane = threadIdx.x & 63;
    int n = blockIdx.x * 4 + wave;
    float acc[NEXP];
#pragma unroll
    for (int e = 0; e < NEXP; e++) acc[e] = 0.f;
    const float* xr = x + (size_t)n * DDIM;
    for (int i = 0; i < DDIM / 64; i++) {
        int d = i * 64 + lane;
        float xv = xr[d];
        const float* wr = Wg + d * NEXP;
#pragma unroll
        for (int e = 0; e < NEXP; e++) acc[e] = fmaf(xv, wr[e], acc[e]);
    }
#pragma unroll
    for (int e = 0; e < NEXP; e++) {
#pragma unroll
        for (int off = 32; off >= 1; off >>= 1)
            acc[e] += __shfl_xor(acc[e], off, 64);
    }
    if (lane == 0) {
        float l0 = -1e30f, l1 = -1e30f; int e0 = 0, e1 = 0;
#pragma unroll
        for (int e = 0; e < NEXP; e++) {
            float v = fmaxf(acc[e], 0.f);   // relu before softmax
            if (v > l0)      { l1 = l0; e1 = e0; l0 = v; e0 = e; }
            else if (v > l1) { l1 = v;  e1 = e; }
        }
        float w0 = 1.f / (1.f + expf(l1 - l0));   // softmax Z cancels in top-2 renorm
        sel[n] = make_int2(e0, e1);
        wts[n] = make_float2(w0, 1.f - w0);
        atomicAdd(&counts[e0], 1);
        atomicAdd(&counts[e1], 1);
    }
}

// scan + build compacted tile table: tile = (expert, slotBase, rows, pad)
__global__ void scan_kernel(const int* __restrict__ counts, int* __restrict__ offsets,
                            int* __restrict__ cursor, int4* __restrict__ tile_meta,
                            int* __restrict__ ntiles) {
    if (threadIdx.x == 0 && blockIdx.x == 0) {
        int s = 0, t = 0;
        for (int e = 0; e < NEXP; e++) {
            offsets[e] = s; cursor[e] = s;
            int c = counts[e];
            for (int r = 0; r < c; r += 128)
                tile_meta[t++] = make_int4(e, s + r, min(128, c - r), 0);
            s += c;
        }
        offsets[NEXP] = s;
        *ntiles = t;
    }
}

__global__ void assign_kernel(const int2* __restrict__ sel, const float2* __restrict__ wts,
                              int* __restrict__ cursor,
                              int* __restrict__ slot_token, float* __restrict__ slot_weight) {
    int n = blockIdx.x * blockDim.x + threadIdx.x;
    if (n >= NTOK) return;
    int2 s = sel[n]; float2 w = wts[n];
    int p0 = atomicAdd(&cursor[s.x], 1);
    slot_token[p0] = n; slot_weight[p0] = w.x;
    int p1 = atomicAdd(&cursor[s.y], 1);
    slot_token[p1] = n; slot_weight[p1] = w.y;
}

// ---------------- fp32 -> bf16 cast of x ----------------
__global__ void cast_x_kernel(const float* __restrict__ x, unsigned short* __restrict__ xb) {
    int i = blockIdx.x * blockDim.x + threadIdx.x;
    float4 v = ((const float4*)x)[i];
    ushort4 o;
    o.x = f2bf(v.x); o.y = f2bf(v.y); o.z = f2bf(v.z); o.w = f2bf(v.w);
    ((ushort4*)xb)[i] = o;
}

// ---------------- transpose+cast: src [R][C] fp32 -> dst [C][R] bf16, per expert (z) ----
// 64x64 tile, float4 reads, ushort8 (16B) writes.
__global__ void transpose_cast_kernel(const float* __restrict__ src, unsigned short* __restrict__ dst,
                                      int R, int C) {
    __shared__ float tile[64][65];
    int e = blockIdx.z;
    const float* s = src + (size_t)e * R * C;
    unsigned short* d = dst + (size_t)e * R * C;
    int t = threadIdx.x;                      // 256 threads
    int r0 = blockIdx.y * 64, c0 = blockIdx.x * 64;
#pragma unroll
    for (int p = 0; p < 4; p++) {
        int r = p * 16 + (t >> 4);
        int c = (t & 15) * 4;
        float4 v = *(const float4*)&s[(size_t)(r0 + r) * C + (c0 + c)];
        tile[r][c] = v.x; tile[r][c + 1] = v.y; tile[r][c + 2] = v.z; tile[r][c + 3] = v.w;
    }
    __syncthreads();
    int c = t >> 2, rb = (t & 3) * 16;
#pragma unroll
    for (int j = 0; j < 2; j++) {
        ushort8v v;
#pragma unroll
        for (int i = 0; i < 8; i++) v[i] = f2bf(tile[rb + j * 8 + i][c]);
        *(ushort8v*)&d[(size_t)(c0 + c) * R + (r0 + rb + j * 8)] = v;
    }
}

// ---------------- tiled MFMA GEMM over compacted expert tiles ----------------
// 128x128 tile, BK=64, XOR-swizzled LDS (16B units: slot s holds global unit s^(row&7)).
// MODE 1: A = xb gathered via slot_token, B = W1T[e][H][D]; epi: +b1, relu, store bf16 h
// MODE 2: A = h rows (contiguous slots), B = W2T[e][O][H]; epi: +b2, relu, *w, atomicAdd out
template <int MODE, int KDIM, int NDIM>
__global__ __launch_bounds__(256) void moe_gemm_kernel(
    const unsigned short* __restrict__ A,
    const unsigned short* __restrict__ B,
    const float* __restrict__ bias,
    const int4* __restrict__ tile_meta,
    const int* __restrict__ ntiles,
    const int* __restrict__ slot_token,
    const float* __restrict__ slot_weight,
    unsigned short* __restrict__ h,
    float* __restrict__ out) {

    if ((int)blockIdx.x >= *ntiles) return;
    int4 tm = tile_meta[blockIdx.x];
    int e = tm.x, slotBase = tm.y, rows = tm.z;
    int colBase = blockIdx.y * 128;

    __shared__ __align__(16) unsigned short As[128 * 64];   // 16 KiB
    __shared__ __align__(16) unsigned short Bs[128 * 64];   // 16 KiB

    int tid = threadIdx.x;
    int w = tid >> 6, l = tid & 63;
    int quad = l >> 4, lr = l & 15;
    int wm = w & 1, wn = w >> 1;
    int lr8 = l >> 3, u = l & 7;
    int gu = u ^ lr8;                         // swizzled global 16B-unit this lane stages

    // each wave stages rows 32w..32w+31; instr j covers rows 32w+8j..+7 (8 rows x 128 B)
    const unsigned short* ag[4];
    const unsigned short* bg[4];
    const unsigned short* Be = B + (size_t)e * NDIM * KDIM;
#pragma unroll
    for (int j = 0; j < 4; j++) {
        int r = 32 * w + 8 * j + lr8;
        int slot = min(slotBase + r, NSLOT - 1);
        if constexpr (MODE == 1) {
            int tok = slot_token[slot];
            ag[j] = A + (size_t)tok * KDIM + gu * 8;
        } else {
            ag[j] = A + (size_t)slot * KDIM + gu * 8;
        }
        bg[j] = Be + (size_t)(colBase + r) * KDIM + gu * 8;
    }

    unsigned short* AsW = As + 32 * w * 64;
    unsigned short* BsW = Bs + 32 * w * 64;

    f32x4 zero = {0.f, 0.f, 0.f, 0.f};
    f32x4 acc[4][4];
#pragma unroll
    for (int m = 0; m < 4; m++)
#pragma unroll
        for (int n = 0; n < 4; n++) acc[m][n] = zero;

    int swz = (lr & 7);
    for (int k0 = 0; k0 < KDIM; k0 += 64) {
#pragma unroll
        for (int j = 0; j < 4; j++)
            __builtin_amdgcn_global_load_lds((gas_ptr)(ag[j] + k0), (las_ptr)(AsW + j * 512), 16, 0, 0);
#pragma unroll
        for (int j = 0; j < 4; j++)
            __builtin_amdgcn_global_load_lds((gas_ptr)(bg[j] + k0), (las_ptr)(BsW + j * 512), 16, 0, 0);
        __syncthreads();
#pragma unroll
        for (int ks = 0; ks < 2; ks++) {
            int su = ((ks * 4 + quad) ^ swz) * 8;   // swizzled element offset within row
            bf16x8 af[4], bf[4];
#pragma unroll
            for (int m = 0; m < 4; m++)
                af[m] = *(const bf16x8*)&As[(wm * 64 + m * 16 + lr) * 64 + su];
#pragma unroll
            for (int n = 0; n < 4; n++)
                bf[n] = *(const bf16x8*)&Bs[(wn * 64 + n * 16 + lr) * 64 + su];
#pragma unroll
            for (int m = 0; m < 4; m++)
#pragma unroll
                for (int n = 0; n < 4; n++)
                    acc[m][n] = __builtin_amdgcn_mfma_f32_16x16x32_bf16(af[m], bf[n], acc[m][n], 0, 0, 0);
        }
        __syncthreads();
    }

    if constexpr (MODE == 1) {
        const float* bv = bias + e * NDIM;
#pragma unroll
        for (int n = 0; n < 4; n++) {
            int gc = colBase + wn * 64 + n * 16 + lr;
            float b = bv[gc];
#pragma unroll
            for (int m = 0; m < 4; m++) {
                int rloc = wm * 64 + m * 16 + quad * 4;
#pragma unroll
                for (int i = 0; i < 4; i++) {
                    int r = rloc + i;
                    if (r < rows) {
                        float v = fmaxf(acc[m][n][i] + b, 0.f);
                        h[(size_t)(slotBase + r) * NDIM + gc] = f2bf(v);
                    }
                }
            }
        }
    } else {
        const float* bv = bias + e * NDIM;
#pragma unroll
        for (int m = 0; m < 4; m++) {
            int rloc = wm * 64 + m * 16 + quad * 4;
#pragma unroll
            for (int i = 0; i < 4; i++) {
                int r = rloc + i;
                if (r >= rows) continue;
                int s = slotBase + r;
                int tok = slot_token[s];
                float wgt = slot_weight[s];
                float* orow = out + (size_t)tok * ODIM;
#pragma unroll
                for (int n = 0; n < 4; n++) {
                    int gc = colBase + wn * 64 + n * 16 + lr;
                    float v = fmaxf(acc[m][n][i] + bv[gc], 0.f) * wgt;
                    atomicAdd(&orow[gc], v);
                }
            }
        }
    }
}

extern "C" void kernel_launch(void* const* d_in, const int* in_sizes, int n_in,
                              void* d_out, int out_size, void* d_ws, size_t ws_size,
                              hipStream_t stream) {
    const float* x  = (const float*)d_in[0];
    const float* Wg = (const float*)d_in[1];
    const float* W1 = (const float*)d_in[2];
    const float* b1 = (const float*)d_in[3];
    const float* W2 = (const float*)d_in[4];
    const float* b2 = (const float*)d_in[5];
    float* out = (float*)d_out;

    char* ws = (char*)d_ws;
    int*    counts      = (int*)(ws + 0);
    int*    cursor      = (int*)(ws + 64);
    int*    offsets     = (int*)(ws + 128);
    int*    ntiles      = (int*)(ws + 192);
    int4*   tile_meta   = (int4*)(ws + 256);                 // 72*16 B
    int2*   sel         = (int2*)(ws + 2048);
    float2* wts         = (float2*)(ws + 34816);
    int*    slot_token  = (int*)(ws + 67584);
    float*  slot_weight = (float*)(ws + 100352);
    unsigned short* xb  = (unsigned short*)(ws + 2097152);   //  8 MiB [NTOK][D]
    unsigned short* W1T = (unsigned short*)(ws + 10485760);  // 64 MiB [E][H][D]
    unsigned short* W2T = (unsigned short*)(ws + 77594624);  // 64 MiB [E][O][H]
    unsigned short* hbf = (unsigned short*)(ws + 144703488); // 64 MiB [NSLOT][H]

    hipMemsetAsync(d_out, 0, (size_t)NTOK * ODIM * sizeof(float), stream);
    hipMemsetAsync(ws, 0, 256, stream);

    gate_kernel<<<NTOK / 4, 256, 0, stream>>>(x, Wg, sel, wts, counts);
    scan_kernel<<<1, 64, 0, stream>>>(counts, offsets, cursor, tile_meta, ntiles);
    assign_kernel<<<NTOK / 256, 256, 0, stream>>>(sel, wts, cursor, slot_token, slot_weight);

    cast_x_kernel<<<(NTOK * DDIM / 4) / 256, 256, 0, stream>>>(x, xb);
    transpose_cast_kernel<<<dim3(HDIM / 64, DDIM / 64, NEXP), 256, 0, stream>>>(W1, W1T, DDIM, HDIM);
    transpose_cast_kernel<<<dim3(ODIM / 64, HDIM / 64, NEXP), 256, 0, stream>>>(W2, W2T, HDIM, ODIM);

    moe_gemm_kernel<1, DDIM, HDIM><<<dim3(MAXTILES, HDIM / 128), 256, 0, stream>>>(
        xb, W1T, b1, tile_meta, ntiles, slot_token, slot_weight, hbf, nullptr);
    moe_gemm_kernel<2, HDIM, ODIM><<<dim3(MAXTILES, ODIM / 128), 256, 0, stream>>>(
        hbf, W2T, b2, tile_meta, ntiles, slot_token, slot_weight, nullptr, out);
}

// Round 3
// 775.328 us; speedup vs baseline: 1.6405x; 1.0402x over previous
//
#include <hip/hip_runtime.h>
#include <cstdint>

#define NTOK 4096
#define DDIM 1024
#define HDIM 4096
#define ODIM 1024
#define NEXP 8
#define NSLOT (2*NTOK)
#define MAXTILES 72

typedef __bf16 bf16x8 __attribute__((ext_vector_type(8)));
typedef float  f32x4  __attribute__((ext_vector_type(4)));
typedef unsigned short ushort8v __attribute__((ext_vector_type(8)));

__device__ __forceinline__ unsigned short f2bf(float f) {
    union { float f; unsigned int u; } v; v.f = f;
    unsigned int r = (v.u + 0x7FFF + ((v.u >> 16) & 1)) >> 16;
    return (unsigned short)r;
}

typedef const void __attribute__((address_space(1)))* gas_ptr;
typedef void       __attribute__((address_space(3)))* las_ptr;

// ---- gate: logits = relu(x@Wg), top-2 (lowest-index tie-break), + fused x->bf16 cast ----
__global__ void gate_kernel(const float* __restrict__ x, const float* __restrict__ Wg,
                            int2* __restrict__ sel, float2* __restrict__ wts,
                            int* __restrict__ counts, unsigned short* __restrict__ xb) {
    int wave = threadIdx.x >> 6;
    int lane = threadIdx.x & 63;
    int n = blockIdx.x * 4 + wave;
    float acc[NEXP];
#pragma unroll
    for (int e = 0; e < NEXP; e++) acc[e] = 0.f;
    const float* xr = x + (size_t)n * DDIM;
    unsigned short* xbr = xb + (size_t)n * DDIM;
    for (int i = 0; i < DDIM / 64; i++) {
        int d = i * 64 + lane;
        float xv = xr[d];
        xbr[d] = f2bf(xv);                    // fused cast
        const float* wr = Wg + d * NEXP;
#pragma unroll
        for (int e = 0; e < NEXP; e++) acc[e] = fmaf(xv, wr[e], acc[e]);
    }
#pragma unroll
    for (int e = 0; e < NEXP; e++) {
#pragma unroll
        for (int off = 32; off >= 1; off >>= 1)
            acc[e] += __shfl_xor(acc[e], off, 64);
    }
    if (lane == 0) {
        float l0 = -1e30f, l1 = -1e30f; int e0 = 0, e1 = 0;
#pragma unroll
        for (int e = 0; e < NEXP; e++) {
            float v = fmaxf(acc[e], 0.f);     // relu before softmax
            if (v > l0)      { l1 = l0; e1 = e0; l0 = v; e0 = e; }
            else if (v > l1) { l1 = v;  e1 = e; }
        }
        float w0 = 1.f / (1.f + expf(l1 - l0));   // softmax Z cancels in top-2 renorm
        sel[n] = make_int2(e0, e1);
        wts[n] = make_float2(w0, 1.f - w0);
        atomicAdd(&counts[e0], 1);
        atomicAdd(&counts[e1], 1);
    }
}

// ---- route: scan counts -> offsets/tile table, then parallel slot assignment ----
__global__ void route_kernel(const int2* __restrict__ sel, const float2* __restrict__ wts,
                             const int* __restrict__ counts, int* __restrict__ offsets,
                             int4* __restrict__ tile_meta, int* __restrict__ ntiles,
                             int* __restrict__ slot_token, float* __restrict__ slot_weight) {
    __shared__ int cur[NEXP];
    int t = threadIdx.x;
    if (t == 0) {
        int s = 0, nt = 0;
        for (int e = 0; e < NEXP; e++) {
            offsets[e] = s; cur[e] = s;
            int c = counts[e];
            for (int r = 0; r < c; r += 128)
                tile_meta[nt++] = make_int4(e, s + r, min(128, c - r), 0);
            s += c;
        }
        offsets[NEXP] = s;
        *ntiles = nt;
    }
    __syncthreads();
    for (int n = t; n < NTOK; n += blockDim.x) {
        int2 se = sel[n]; float2 w = wts[n];
        int p0 = atomicAdd(&cur[se.x], 1);
        slot_token[p0] = n; slot_weight[p0] = w.x;
        int p1 = atomicAdd(&cur[se.y], 1);
        slot_token[p1] = n; slot_weight[p1] = w.y;
    }
}

// ---- transpose+cast: src [R][C] fp32 -> dst [C][R] bf16, per expert (z) ----
__global__ void transpose_cast_kernel(const float* __restrict__ src, unsigned short* __restrict__ dst,
                                      int R, int C) {
    __shared__ float tile[64][65];
    int e = blockIdx.z;
    const float* s = src + (size_t)e * R * C;
    unsigned short* d = dst + (size_t)e * R * C;
    int t = threadIdx.x;                      // 256 threads
    int r0 = blockIdx.y * 64, c0 = blockIdx.x * 64;
#pragma unroll
    for (int p = 0; p < 4; p++) {
        int r = p * 16 + (t >> 4);
        int c = (t & 15) * 4;
        float4 v = *(const float4*)&s[(size_t)(r0 + r) * C + (c0 + c)];
        tile[r][c] = v.x; tile[r][c + 1] = v.y; tile[r][c + 2] = v.z; tile[r][c + 3] = v.w;
    }
    __syncthreads();
    int c = t >> 2, rb = (t & 3) * 16;
#pragma unroll
    for (int j = 0; j < 2; j++) {
        ushort8v v;
#pragma unroll
        for (int i = 0; i < 8; i++) v[i] = f2bf(tile[rb + j * 8 + i][c]);
        *(ushort8v*)&d[(size_t)(c0 + c) * R + (r0 + rb + j * 8)] = v;
    }
}

// ---- software-pipelined MFMA GEMM: 128x128 tile, BK=64, double-buffered LDS, ----
// ---- raw s_barrier + manual vmcnt so next tile's loads stay in flight.       ----
// grid.x = colblock (XCD affinity: same-B-panel blocks land on same XCD), grid.y = tile
// MODE 1: A = xb gathered via slot_token, B = W1T[e][H][D]; epi: +b1, relu, store bf16 h
// MODE 2: A = h rows (contiguous slots), B = W2T[e][O][H]; epi: +b2, relu, *w, atomicAdd out
template <int MODE, int KDIM, int NDIM>
__global__ __launch_bounds__(256) void moe_gemm_kernel(
    const unsigned short* __restrict__ A,
    const unsigned short* __restrict__ B,
    const float* __restrict__ bias,
    const int4* __restrict__ tile_meta,
    const int* __restrict__ ntiles,
    const int* __restrict__ slot_token,
    const float* __restrict__ slot_weight,
    unsigned short* __restrict__ h,
    float* __restrict__ out) {

    if ((int)blockIdx.y >= *ntiles) return;
    int4 tm = tile_meta[blockIdx.y];
    int e = tm.x, slotBase = tm.y, rows = tm.z;
    int colBase = blockIdx.x * 128;

    __shared__ __align__(16) unsigned short As[2][128 * 64];   // 2 x 16 KiB
    __shared__ __align__(16) unsigned short Bs[2][128 * 64];   // 2 x 16 KiB

    int tid = threadIdx.x;
    int w = tid >> 6, l = tid & 63;
    int quad = l >> 4, lr = l & 15;
    int wm = w & 1, wn = w >> 1;
    int lr8 = l >> 3, u = l & 7;
    int gu = u ^ lr8;                         // swizzled global 16B-unit this lane stages

    const unsigned short* ag[4];
    const unsigned short* bg[4];
    const unsigned short* Be = B + (size_t)e * NDIM * KDIM;
#pragma unroll
    for (int j = 0; j < 4; j++) {
        int r = 32 * w + 8 * j + lr8;
        int slot = min(slotBase + r, NSLOT - 1);
        if constexpr (MODE == 1) {
            int tok = slot_token[slot];
            ag[j] = A + (size_t)tok * KDIM + gu * 8;
        } else {
            ag[j] = A + (size_t)slot * KDIM + gu * 8;
        }
        bg[j] = Be + (size_t)(colBase + r) * KDIM + gu * 8;
    }

    f32x4 zero = {0.f, 0.f, 0.f, 0.f};
    f32x4 acc[4][4];
#pragma unroll
    for (int m = 0; m < 4; m++)
#pragma unroll
        for (int n = 0; n < 4; n++) acc[m][n] = zero;

    int swz = (lr & 7);
    constexpr int NI = KDIM / 64;

    auto issue = [&](int k, int s) {
        unsigned short* AsW = &As[s][32 * w * 64];
        unsigned short* BsW = &Bs[s][32 * w * 64];
#pragma unroll
        for (int j = 0; j < 4; j++)
            __builtin_amdgcn_global_load_lds((gas_ptr)(ag[j] + k * 64), (las_ptr)(AsW + j * 512), 16, 0, 0);
#pragma unroll
        for (int j = 0; j < 4; j++)
            __builtin_amdgcn_global_load_lds((gas_ptr)(bg[j] + k * 64), (las_ptr)(BsW + j * 512), 16, 0, 0);
    };
    auto compute = [&](int s) {
        const unsigned short* A_ = As[s];
        const unsigned short* B_ = Bs[s];
#pragma unroll
        for (int ks = 0; ks < 2; ks++) {
            int su = ((ks * 4 + quad) ^ swz) * 8;
            bf16x8 af[4], bf[4];
#pragma unroll
            for (int m = 0; m < 4; m++)
                af[m] = *(const bf16x8*)&A_[(wm * 64 + m * 16 + lr) * 64 + su];
#pragma unroll
            for (int n = 0; n < 4; n++)
                bf[n] = *(const bf16x8*)&B_[(wn * 64 + n * 16 + lr) * 64 + su];
#pragma unroll
            for (int m = 0; m < 4; m++)
#pragma unroll
                for (int n = 0; n < 4; n++)
                    acc[m][n] = __builtin_amdgcn_mfma_f32_16x16x32_bf16(af[m], bf[n], acc[m][n], 0, 0, 0);
        }
    };

    issue(0, 0);
    for (int k = 0; k < NI - 1; k++) {
        issue(k + 1, (k + 1) & 1);
        asm volatile("s_waitcnt vmcnt(8)" ::: "memory");   // tile k's 8 loads done; k+1's stay in flight
        asm volatile("s_barrier" ::: "memory");
        compute(k & 1);
        asm volatile("s_barrier" ::: "memory");            // all reads of buf (k&1) done before overwrite
    }
    asm volatile("s_waitcnt vmcnt(0)" ::: "memory");
    asm volatile("s_barrier" ::: "memory");
    compute((NI - 1) & 1);

    if constexpr (MODE == 1) {
        const float* bv = bias + e * NDIM;
#pragma unroll
        for (int n = 0; n < 4; n++) {
            int gc = colBase + wn * 64 + n * 16 + lr;
            float b = bv[gc];
#pragma unroll
            for (int m = 0; m < 4; m++) {
                int rloc = wm * 64 + m * 16 + quad * 4;
#pragma unroll
                for (int i = 0; i < 4; i++) {
                    int r = rloc + i;
                    if (r < rows) {
                        float v = fmaxf(acc[m][n][i] + b, 0.f);
                        h[(size_t)(slotBase + r) * NDIM + gc] = f2bf(v);
                    }
                }
            }
        }
    } else {
        const float* bv = bias + e * NDIM;
#pragma unroll
        for (int m = 0; m < 4; m++) {
            int rloc = wm * 64 + m * 16 + quad * 4;
#pragma unroll
            for (int i = 0; i < 4; i++) {
                int r = rloc + i;
                if (r >= rows) continue;
                int s = slotBase + r;
                int tok = slot_token[s];
                float wgt = slot_weight[s];
                float* orow = out + (size_t)tok * ODIM;
#pragma unroll
                for (int n = 0; n < 4; n++) {
                    int gc = colBase + wn * 64 + n * 16 + lr;
                    float v = fmaxf(acc[m][n][i] + bv[gc], 0.f) * wgt;
                    atomicAdd(&orow[gc], v);
                }
            }
        }
    }
}

extern "C" void kernel_launch(void* const* d_in, const int* in_sizes, int n_in,
                              void* d_out, int out_size, void* d_ws, size_t ws_size,
                              hipStream_t stream) {
    const float* x  = (const float*)d_in[0];
    const float* Wg = (const float*)d_in[1];
    const float* W1 = (const float*)d_in[2];
    const float* b1 = (const float*)d_in[3];
    const float* W2 = (const float*)d_in[4];
    const float* b2 = (const float*)d_in[5];
    float* out = (float*)d_out;

    char* ws = (char*)d_ws;
    int*    counts      = (int*)(ws + 0);
    int*    offsets     = (int*)(ws + 128);
    int*    ntiles      = (int*)(ws + 192);
    int4*   tile_meta   = (int4*)(ws + 256);                 // 72*16 B
    int2*   sel         = (int2*)(ws + 2048);
    float2* wts         = (float2*)(ws + 34816);
    int*    slot_token  = (int*)(ws + 67584);
    float*  slot_weight = (float*)(ws + 100352);
    unsigned short* xb  = (unsigned short*)(ws + 2097152);   //  8 MiB [NTOK][D]
    unsigned short* W1T = (unsigned short*)(ws + 10485760);  // 64 MiB [E][H][D]
    unsigned short* W2T = (unsigned short*)(ws + 77594624);  // 64 MiB [E][O][H]
    unsigned short* hbf = (unsigned short*)(ws + 144703488); // 64 MiB [NSLOT][H]

    hipMemsetAsync(d_out, 0, (size_t)NTOK * ODIM * sizeof(float), stream);
    hipMemsetAsync(ws, 0, 256, stream);

    gate_kernel<<<NTOK / 4, 256, 0, stream>>>(x, Wg, sel, wts, counts, xb);
    route_kernel<<<1, 512, 0, stream>>>(sel, wts, counts, offsets, tile_meta, ntiles,
                                        slot_token, slot_weight);

    transpose_cast_kernel<<<dim3(HDIM / 64, DDIM / 64, NEXP), 256, 0, stream>>>(W1, W1T, DDIM, HDIM);
    transpose_cast_kernel<<<dim3(ODIM / 64, HDIM / 64, NEXP), 256, 0, stream>>>(W2, W2T, HDIM, ODIM);

    moe_gemm_kernel<1, DDIM, HDIM><<<dim3(HDIM / 128, MAXTILES), 256, 0, stream>>>(
        xb, W1T, b1, tile_meta, ntiles, slot_token, slot_weight, hbf, nullptr);
    moe_gemm_kernel<2, HDIM, ODIM><<<dim3(ODIM / 128, MAXTILES), 256, 0, stream>>>(
        hbf, W2T, b2, tile_meta, ntiles, slot_token, slot_weight, nullptr, out);
}

// Round 4
// 773.106 us; speedup vs baseline: 1.6452x; 1.0029x over previous
//
#include <hip/hip_runtime.h>
#include <cstdint>

#define NTOK 4096
#define DDIM 1024
#define HDIM 4096
#define ODIM 1024
#define NEXP 8
#define NSLOT (2*NTOK)
#define MAXT128 72
#define MAXT256 40

typedef __bf16 bf16x8 __attribute__((ext_vector_type(8)));
typedef float  f32x4  __attribute__((ext_vector_type(4)));
typedef unsigned short ushort8v __attribute__((ext_vector_type(8)));

__device__ __forceinline__ unsigned short f2bf(float f) {
    union { float f; unsigned int u; } v; v.f = f;
    unsigned int r = (v.u + 0x7FFF + ((v.u >> 16) & 1)) >> 16;
    return (unsigned short)r;
}

typedef const void __attribute__((address_space(1)))* gas_ptr;
typedef void       __attribute__((address_space(3)))* las_ptr;

// ---- gate: logits = relu(x@Wg), top-2 (lowest-index tie-break), fused x->bf16 cast ----
__global__ void gate_kernel(const float* __restrict__ x, const float* __restrict__ Wg,
                            int2* __restrict__ sel, float2* __restrict__ wts,
                            int* __restrict__ counts, unsigned short* __restrict__ xb) {
    int wave = threadIdx.x >> 6;
    int lane = threadIdx.x & 63;
    int n = blockIdx.x * 4 + wave;
    float acc[NEXP];
#pragma unroll
    for (int e = 0; e < NEXP; e++) acc[e] = 0.f;
    const float* xr = x + (size_t)n * DDIM;
    unsigned short* xbr = xb + (size_t)n * DDIM;
#pragma unroll
    for (int i = 0; i < 4; i++) {
        int d = i * 256 + lane * 4;
        float4 xv = *(const float4*)&xr[d];
        ushort4 o;
        o.x = f2bf(xv.x); o.y = f2bf(xv.y); o.z = f2bf(xv.z); o.w = f2bf(xv.w);
        *(ushort4*)&xbr[d] = o;
        const float* wr = Wg + (size_t)d * NEXP;
#pragma unroll
        for (int jj = 0; jj < 4; jj++) {
            float xs = (jj == 0) ? xv.x : (jj == 1) ? xv.y : (jj == 2) ? xv.z : xv.w;
#pragma unroll
            for (int e = 0; e < NEXP; e++)
                acc[e] = fmaf(xs, wr[jj * NEXP + e], acc[e]);
        }
    }
#pragma unroll
    for (int e = 0; e < NEXP; e++) {
#pragma unroll
        for (int off = 32; off >= 1; off >>= 1)
            acc[e] += __shfl_xor(acc[e], off, 64);
    }
    if (lane == 0) {
        float l0 = -1e30f, l1 = -1e30f; int e0 = 0, e1 = 0;
#pragma unroll
        for (int e = 0; e < NEXP; e++) {
            float v = fmaxf(acc[e], 0.f);     // relu before softmax
            if (v > l0)      { l1 = l0; e1 = e0; l0 = v; e0 = e; }
            else if (v > l1) { l1 = v;  e1 = e; }
        }
        float w0 = 1.f / (1.f + expf(l1 - l0));   // softmax Z cancels in top-2 renorm
        sel[n] = make_int2(e0, e1);
        wts[n] = make_float2(w0, 1.f - w0);
        atomicAdd(&counts[e0], 1);
        atomicAdd(&counts[e1], 1);
    }
}

// ---- route: scan counts -> offsets + 128-tile and 256-tile tables, slot assignment ----
__global__ void route_kernel(const int2* __restrict__ sel, const float2* __restrict__ wts,
                             const int* __restrict__ counts, int* __restrict__ offsets,
                             int4* __restrict__ t128, int* __restrict__ nt128,
                             int4* __restrict__ t256, int* __restrict__ nt256,
                             int* __restrict__ slot_token, float* __restrict__ slot_weight) {
    __shared__ int cur[NEXP];
    int t = threadIdx.x;
    if (t == 0) {
        int s = 0, n1 = 0, n2 = 0;
        for (int e = 0; e < NEXP; e++) {
            offsets[e] = s; cur[e] = s;
            int c = counts[e];
            for (int r = 0; r < c; r += 128)
                t128[n1++] = make_int4(e, s + r, min(128, c - r), 0);
            for (int r = 0; r < c; r += 256)
                t256[n2++] = make_int4(e, s + r, min(256, c - r), 0);
            s += c;
        }
        offsets[NEXP] = s;
        *nt128 = n1; *nt256 = n2;
    }
    __syncthreads();
    for (int n = t; n < NTOK; n += blockDim.x) {
        int2 se = sel[n]; float2 w = wts[n];
        int p0 = atomicAdd(&cur[se.x], 1);
        slot_token[p0] = n; slot_weight[p0] = w.x;
        int p1 = atomicAdd(&cur[se.y], 1);
        slot_token[p1] = n; slot_weight[p1] = w.y;
    }
}

// ---- transpose+cast: src [R][C] fp32 -> dst [C][R] bf16, per expert (z) ----
__global__ void transpose_cast_kernel(const float* __restrict__ src, unsigned short* __restrict__ dst,
                                      int R, int C) {
    __shared__ float tile[64][65];
    int e = blockIdx.z;
    const float* s = src + (size_t)e * R * C;
    unsigned short* d = dst + (size_t)e * R * C;
    int t = threadIdx.x;                      // 256 threads
    int r0 = blockIdx.y * 64, c0 = blockIdx.x * 64;
#pragma unroll
    for (int p = 0; p < 4; p++) {
        int r = p * 16 + (t >> 4);
        int c = (t & 15) * 4;
        float4 v = *(const float4*)&s[(size_t)(r0 + r) * C + (c0 + c)];
        tile[r][c] = v.x; tile[r][c + 1] = v.y; tile[r][c + 2] = v.z; tile[r][c + 3] = v.w;
    }
    __syncthreads();
    int c = t >> 2, rb = (t & 3) * 16;
#pragma unroll
    for (int j = 0; j < 2; j++) {
        ushort8v v;
#pragma unroll
        for (int i = 0; i < 8; i++) v[i] = f2bf(tile[rb + j * 8 + i][c]);
        *(ushort8v*)&d[(size_t)(c0 + c) * R + (r0 + rb + j * 8)] = v;
    }
}

// ---- software-pipelined MFMA GEMM, TM x TN tile, BK=32, dbuf LDS, XCD-aware grid ----
// MODE 1 (128x256): grid=(NDIM/TN, MAXT128); A gathered via slot_token; epi: +b1,relu,bf16 h
// MODE 2 (256x128): grid=(8, MAXT256); tile = x + 8*(y>>3), col = y&7 (per-XCD A-tile
//                   residency, cols inner); epi: +b2, relu, *wgt, atomicAdd out
template <int MODE, int KDIM, int NDIM, int TM, int TN, int WMv>
__global__ __launch_bounds__(256, 2) void moe_gemm_kernel(
    const unsigned short* __restrict__ A,
    const unsigned short* __restrict__ B,
    const float* __restrict__ bias,
    const int4* __restrict__ tile_meta,
    const int* __restrict__ ntiles,
    const int* __restrict__ slot_token,
    const float* __restrict__ slot_weight,
    unsigned short* __restrict__ h,
    float* __restrict__ out) {

    int tileIdx, colBase;
    if constexpr (MODE == 1) {
        tileIdx = blockIdx.y;
        colBase = blockIdx.x * TN;
    } else {
        int j = blockIdx.y;
        tileIdx = blockIdx.x + 8 * (j >> 3);
        colBase = (j & 7) * TN;
    }
    if (tileIdx >= *ntiles) return;
    int4 tm = tile_meta[tileIdx];
    int e = tm.x, slotBase = tm.y, rows = tm.z;

    constexpr int RA = TM / 4, IA = RA / 16;   // A rows/wave, instrs/wave
    constexpr int RB = TN / 4, IB = RB / 16;
    constexpr int NI = KDIM / 32;

    __shared__ __align__(16) unsigned short As[2][TM * 32];
    __shared__ __align__(16) unsigned short Bs[2][TN * 32];

    int tid = threadIdx.x;
    int w = tid >> 6, l = tid & 63;
    int quad = l >> 4, lr = l & 15;
    int wm = w % WMv, wn = w / WMv;

    // staging: lane l covers row (l>>2) of its 16-row chunk; swizzled 16B unit
    int rl = l >> 2;
    int g = (l & 3) ^ ((l >> 3) & 3);          // LDS slot (r,u) holds global unit u^((r>>1)&3)

    const unsigned short* ag[IA];
    const unsigned short* bg[IB];
    const unsigned short* Be = B + (size_t)e * NDIM * KDIM;
#pragma unroll
    for (int j = 0; j < IA; j++) {
        int r = w * RA + j * 16 + rl;
        int slot = min(slotBase + r, NSLOT - 1);
        if constexpr (MODE == 1) {
            int tok = slot_token[slot];
            ag[j] = A + (size_t)tok * KDIM + g * 8;
        } else {
            ag[j] = A + (size_t)slot * KDIM + g * 8;
        }
    }
#pragma unroll
    for (int j = 0; j < IB; j++) {
        int r = w * RB + j * 16 + rl;
        bg[j] = Be + (size_t)(colBase + r) * KDIM + g * 8;
    }

    f32x4 zero = {0.f, 0.f, 0.f, 0.f};
    f32x4 acc[8][4];
#pragma unroll
    for (int m = 0; m < 8; m++)
#pragma unroll
        for (int n = 0; n < 4; n++) acc[m][n] = zero;

    int su = (quad ^ ((lr >> 1) & 3)) * 16;    // swizzled byte offset within 64B row

    auto issue = [&](int k, int s) {
        unsigned short* AsW = &As[s][w * RA * 32];
        unsigned short* BsW = &Bs[s][w * RB * 32];
#pragma unroll
        for (int j = 0; j < IA; j++)
            __builtin_amdgcn_global_load_lds((gas_ptr)(ag[j] + k * 32), (las_ptr)(AsW + j * 512), 16, 0, 0);
#pragma unroll
        for (int j = 0; j < IB; j++)
            __builtin_amdgcn_global_load_lds((gas_ptr)(bg[j] + k * 32), (las_ptr)(BsW + j * 512), 16, 0, 0);
    };
    auto compute = [&](int s) {
        const char* A_ = (const char*)As[s];
        const char* B_ = (const char*)Bs[s];
        bf16x8 af[8], bf[4];
#pragma unroll
        for (int m = 0; m < 8; m++)
            af[m] = *(const bf16x8*)(A_ + (wm * 128 + m * 16 + lr) * 64 + su);
#pragma unroll
        for (int n = 0; n < 4; n++)
            bf[n] = *(const bf16x8*)(B_ + (wn * 64 + n * 16 + lr) * 64 + su);
#pragma unroll
        for (int m = 0; m < 8; m++)
#pragma unroll
            for (int n = 0; n < 4; n++)
                acc[m][n] = __builtin_amdgcn_mfma_f32_16x16x32_bf16(af[m], bf[n], acc[m][n], 0, 0, 0);
    };

    issue(0, 0);
    for (int k = 0; k < NI - 1; k++) {
        issue(k + 1, (k + 1) & 1);
        asm volatile("s_waitcnt vmcnt(6)" ::: "memory");   // tile k ready; k+1 in flight
        asm volatile("s_barrier" ::: "memory");
        compute(k & 1);
        asm volatile("s_barrier" ::: "memory");
    }
    asm volatile("s_waitcnt vmcnt(0)" ::: "memory");
    asm volatile("s_barrier" ::: "memory");
    compute((NI - 1) & 1);

    if constexpr (MODE == 1) {
        const float* bv = bias + e * NDIM;
#pragma unroll
        for (int n = 0; n < 4; n++) {
            int gc = colBase + wn * 64 + n * 16 + lr;
            float b = bv[gc];
#pragma unroll
            for (int m = 0; m < 8; m++) {
                int rloc = wm * 128 + m * 16 + quad * 4;
#pragma unroll
                for (int i = 0; i < 4; i++) {
                    int r = rloc + i;
                    if (r < rows) {
                        float v = fmaxf(acc[m][n][i] + b, 0.f);
                        h[(size_t)(slotBase + r) * NDIM + gc] = f2bf(v);
                    }
                }
            }
        }
    } else {
        const float* bv = bias + e * NDIM;
#pragma unroll
        for (int m = 0; m < 8; m++) {
            int rloc = wm * 128 + m * 16 + quad * 4;
#pragma unroll
            for (int i = 0; i < 4; i++) {
                int r = rloc + i;
                if (r >= rows) continue;
                int s = slotBase + r;
                int tok = slot_token[s];
                float wgt = slot_weight[s];
                float* orow = out + (size_t)tok * ODIM;
#pragma unroll
                for (int n = 0; n < 4; n++) {
                    int gc = colBase + wn * 64 + n * 16 + lr;
                    float v = fmaxf(acc[m][n][i] + bv[gc], 0.f) * wgt;
                    atomicAdd(&orow[gc], v);
                }
            }
        }
    }
}

extern "C" void kernel_launch(void* const* d_in, const int* in_sizes, int n_in,
                              void* d_out, int out_size, void* d_ws, size_t ws_size,
                              hipStream_t stream) {
    const float* x  = (const float*)d_in[0];
    const float* Wg = (const float*)d_in[1];
    const float* W1 = (const float*)d_in[2];
    const float* b1 = (const float*)d_in[3];
    const float* W2 = (const float*)d_in[4];
    const float* b2 = (const float*)d_in[5];
    float* out = (float*)d_out;

    char* ws = (char*)d_ws;
    int*    counts      = (int*)(ws + 0);
    int*    offsets     = (int*)(ws + 64);
    int*    nt128       = (int*)(ws + 128);
    int*    nt256       = (int*)(ws + 132);
    int4*   t128        = (int4*)(ws + 256);
    int4*   t256        = (int4*)(ws + 2048);
    int2*   sel         = (int2*)(ws + 4096);
    float2* wts         = (float2*)(ws + 36864);
    int*    slot_token  = (int*)(ws + 69632);
    float*  slot_weight = (float*)(ws + 102400);
    unsigned short* xb  = (unsigned short*)(ws + 2097152);   //  8 MiB [NTOK][D]
    unsigned short* W1T = (unsigned short*)(ws + 10485760);  // 64 MiB [E][H][D]
    unsigned short* W2T = (unsigned short*)(ws + 77594624);  // 64 MiB [E][O][H]
    unsigned short* hbf = (unsigned short*)(ws + 144703488); // 64 MiB [NSLOT][H]

    hipMemsetAsync(d_out, 0, (size_t)NTOK * ODIM * sizeof(float), stream);
    hipMemsetAsync(ws, 0, 256, stream);

    gate_kernel<<<NTOK / 4, 256, 0, stream>>>(x, Wg, sel, wts, counts, xb);
    route_kernel<<<1, 512, 0, stream>>>(sel, wts, counts, offsets, t128, nt128, t256, nt256,
                                        slot_token, slot_weight);

    transpose_cast_kernel<<<dim3(HDIM / 64, DDIM / 64, NEXP), 256, 0, stream>>>(W1, W1T, DDIM, HDIM);
    transpose_cast_kernel<<<dim3(ODIM / 64, HDIM / 64, NEXP), 256, 0, stream>>>(W2, W2T, HDIM, ODIM);

    // GEMM1: 128x256 tiles, waves 1x4; colblock<->XCD affinity (16 % 8 == 0)
    moe_gemm_kernel<1, DDIM, HDIM, 128, 256, 1><<<dim3(HDIM / 256, MAXT128), 256, 0, stream>>>(
        xb, W1T, b1, t128, nt128, slot_token, slot_weight, hbf, nullptr);
    // GEMM2: 256x128 tiles, waves 2x2; per-XCD tile ownership, cols inner
    moe_gemm_kernel<2, HDIM, ODIM, 256, 128, 2><<<dim3(8, MAXT256), 256, 0, stream>>>(
        hbf, W2T, b2, t256, nt256, slot_token, slot_weight, nullptr, out);
}